// Round 4
// baseline (78.001 us; speedup 1.0000x reference)
//
#include <hip/hip_runtime.h>
#include <hip/hip_bf16.h>

#define NB    16
#define NQ    2048
#define NKV   2048
#define DH    128
#define KVT   64
#define NTILE 32          // NKV / KVT
#define TILE_BYTES 16384  // 64*128*2
#define TILE_ELT   8192

typedef __attribute__((ext_vector_type(8))) short short8;
typedef __attribute__((ext_vector_type(4))) float f32x4;

__device__ __forceinline__ unsigned short f2bf(float f) {
    union { float f; unsigned int u; } x; x.f = f;
    unsigned int r = (x.u + 0x7fffu + ((x.u >> 16) & 1u)) >> 16;
    return (unsigned short)r;
}

__device__ __forceinline__ void load_lds16(const void* g, void* l) {
    __builtin_amdgcn_global_load_lds(
        (const __attribute__((address_space(1))) unsigned int*)g,
        (__attribute__((address_space(3))) unsigned int*)l, 16, 0, 0);
}

// ---------------- pre-convert K -> bf16 tiles, V -> V^T bf16 tiles -----------
__global__ __launch_bounds__(256)
void preconv(const float* __restrict__ kg, const float* __restrict__ vg,
             const int* __restrict__ vlg,
             unsigned short* __restrict__ kws, unsigned short* __restrict__ vws) {
    __shared__ __align__(16) unsigned short lv[TILE_ELT];   // 16 KB temp
    const int tid = threadIdx.x;
    const int rb = (blockIdx.x & 7) * 64 + (blockIdx.x >> 3);   // XCD chunking
    const int b = rb >> 5, t = rb & 31;
    const int vl = vlg[b];
    const int ntiles = (vl == 0) ? NTILE : ((vl + KVT - 1) >> 6);
    if (t >= ntiles) return;

    const float* kb = kg + ((size_t)b * NKV + t * KVT) * DH;
    const float* vb = vg + ((size_t)b * NKV + t * KVT) * DH;
    char* kimg = (char*)(kws + (size_t)(b * NTILE + t) * TILE_ELT);
    char* vimg = (char*)(vws + (size_t)(b * NTILE + t) * TILE_ELT);

    #pragma unroll
    for (int p = 0; p < 4; ++p) {
        int idx = p * 256 + tid;
        int row = idx >> 4, ch = idx & 15;
        f32x4 a = *(const f32x4*)(kb + row * DH + ch * 8);
        f32x4 c = *(const f32x4*)(kb + row * DH + ch * 8 + 4);
        union { short8 v; unsigned short u[8]; } w;
        #pragma unroll
        for (int j = 0; j < 4; ++j) { w.u[j] = f2bf(a[j]); w.u[4 + j] = f2bf(c[j]); }
        *(short8*)(kimg + row * 256 + ((ch * 16) ^ ((row & 7) << 4))) = w.v;
        f32x4 va = *(const f32x4*)(vb + row * DH + ch * 8);
        f32x4 vc = *(const f32x4*)(vb + row * DH + ch * 8 + 4);
        union { short8 v; unsigned short u[8]; } w2;
        #pragma unroll
        for (int j = 0; j < 4; ++j) { w2.u[j] = f2bf(va[j]); w2.u[4 + j] = f2bf(vc[j]); }
        *(short8*)((char*)lv + row * 256 + ((ch * 16) ^ (((row >> 3) & 7) << 4))) = w2.v;
    }
    __syncthreads();
    // transpose out: V^T rows d (128B each), coalesced 16B writes
    #pragma unroll
    for (int p = 0; p < 4; ++p) {
        int task = p * 256 + tid;
        int c = task & 7, d = task >> 3;
        union { short8 v; unsigned short u[8]; } w;
        #pragma unroll
        for (int j = 0; j < 8; ++j) {
            int kv = c * 8 + j;
            w.u[j] = *(const unsigned short*)((const char*)lv + kv * 256 + ((d * 2) ^ (((kv >> 3) & 7) << 4)));
        }
        *(short8*)(vimg + d * 128 + ((c * 16) ^ ((d & 7) << 4))) = w.v;
    }
}

// ------- main attention: 4 waves x 32 q-rows, double-buffered K/V -----------
__global__ __launch_bounds__(256, 1)
void attn_fwd4(const float* __restrict__ qg,
               const unsigned short* __restrict__ kws,
               const unsigned short* __restrict__ vws,
               const int* __restrict__ vlg, float* __restrict__ og) {
    __shared__ __align__(16) unsigned short lds_k[2][TILE_ELT];   // 32 KB
    __shared__ __align__(16) unsigned short lds_v[2][TILE_ELT];   // 32 KB
    __shared__ __align__(16) unsigned short lds_p[4][32 * KVT];   // 16 KB

    const int tid = threadIdx.x;
    const int lane = tid & 63;
    const int wv = tid >> 6;
    const int row16 = lane & 15;
    const int g = lane >> 4;

    const int bid = blockIdx.x;
    const int b  = bid >> 4;          // each batch's 16 blocks spread over XCDs
    const int qt = bid & 15;
    const int q0 = qt * 128 + wv * 32;
    const int vl = vlg[b];

    // Q fragments for 2 row-groups; scale folded: (1/sqrt(128)) * log2(e)
    const float QS = 1.4426950408889634f * 0.08838834764831845f;
    short8 qf[2][4];
    #pragma unroll
    for (int m = 0; m < 2; ++m) {
        const float* qp = qg + ((size_t)b * NQ + q0 + m * 16 + row16) * DH + g * 8;
        #pragma unroll
        for (int c = 0; c < 4; ++c) {
            f32x4 a  = *(const f32x4*)(qp + c * 32);
            f32x4 bb = *(const f32x4*)(qp + c * 32 + 4);
            union { short8 v; unsigned short u[8]; } t;
            #pragma unroll
            for (int j = 0; j < 4; ++j) { t.u[j] = f2bf(a[j] * QS); t.u[4 + j] = f2bf(bb[j] * QS); }
            qf[m][c] = t.v;
        }
    }

    const int ntiles = (vl == 0) ? NTILE : ((vl + KVT - 1) >> 6);
    // unnormalized softmax: P = exp2(s); masked -> 0 exactly. vl==0 -> uniform.
    const float MASKV = (vl == 0) ? 0.0f : -1442695.0f;

    f32x4 oacc[2][8];
    f32x4 ellacc[2];
    #pragma unroll
    for (int m = 0; m < 2; ++m) {
        ellacc[m] = (f32x4){0.f, 0.f, 0.f, 0.f};
        #pragma unroll
        for (int n = 0; n < 8; ++n) oacc[m][n] = (f32x4){0.f, 0.f, 0.f, 0.f};
    }
    short8 ones;
    {
        union { short8 v; unsigned short u[8]; } t;
        #pragma unroll
        for (int j = 0; j < 8; ++j) t.u[j] = 0x3F80;  // bf16 1.0
        ones = t.v;
    }

    const char* kbase = (const char*)kws + (size_t)b * NTILE * TILE_BYTES;
    const char* vbase = (const char*)vws + (size_t)b * NTILE * TILE_BYTES;

    auto stage = [&](int t, int nb) {
        const char* ks = kbase + (size_t)t * TILE_BYTES;
        const char* vs = vbase + (size_t)t * TILE_BYTES;
        #pragma unroll
        for (int i = 0; i < 4; ++i) {
            int off = i * 4096 + wv * 1024;
            load_lds16(ks + off + lane * 16, (char*)lds_k[nb] + off);
            load_lds16(vs + off + lane * 16, (char*)lds_v[nb] + off);
        }
    };

    // prologue: tile 0 -> buf 0
    stage(0, 0);
    asm volatile("s_waitcnt vmcnt(0)" ::: "memory");
    __syncthreads();

    int cur = 0;
    const int swzr = ((row16 >> 2) ^ ((row16 & 3) << 1)) & 7;

    for (int tt = 0; tt < ntiles; ++tt) {
        if (tt + 1 < ntiles) stage(tt + 1, cur ^ 1);   // issue-early prefetch

        // ---- QK^T : s[m][n][r] = S[q0+wv*32+m*16+g*4+r][tt*64+n*16+row16] ----
        const char* kbuf = (const char*)lds_k[cur];
        f32x4 s[2][4];
        #pragma unroll
        for (int m = 0; m < 2; ++m)
            #pragma unroll
            for (int n = 0; n < 4; ++n) s[m][n] = (f32x4){0.f, 0.f, 0.f, 0.f};
        __builtin_amdgcn_s_setprio(1);
        #pragma unroll
        for (int c = 0; c < 4; ++c) {
            short8 kf[4];
            #pragma unroll
            for (int n = 0; n < 4; ++n) {
                int krow = n * 16 + row16;
                kf[n] = *(const short8*)(kbuf + krow * 256 +
                                         ((c * 64 + g * 16) ^ ((krow & 7) << 4)));
            }
            #pragma unroll
            for (int n = 0; n < 4; ++n)
                #pragma unroll
                for (int m = 0; m < 2; ++m)
                    s[m][n] = __builtin_amdgcn_mfma_f32_16x16x32_bf16(qf[m][c], kf[n], s[m][n], 0, 0, 0);
        }
        __builtin_amdgcn_s_setprio(0);

        // ---- mask (last tile only; vl==0 masks everything to 0) ----
        if (vl == 0 || tt == ntiles - 1) {
            int kvb = tt * KVT;
            #pragma unroll
            for (int n = 0; n < 4; ++n) {
                if (kvb + n * 16 + row16 >= vl) {
                    #pragma unroll
                    for (int m = 0; m < 2; ++m)
                        #pragma unroll
                        for (int r = 0; r < 4; ++r) s[m][n][r] = MASKV;
                }
            }
        }

        // ---- P = exp2(s), write to per-wave LDS (swizzled) ----
        #pragma unroll
        for (int m = 0; m < 2; ++m)
            #pragma unroll
            for (int n = 0; n < 4; ++n)
                #pragma unroll
                for (int r = 0; r < 4; ++r) {
                    float p = __builtin_amdgcn_exp2f(s[m][n][r]);
                    int qr = m * 16 + g * 4 + r;
                    int swz = (g ^ (r << 1)) & 7;
                    __hip_bfloat16 h = __float2bfloat16(p);
                    *(unsigned short*)((char*)lds_p[wv] + qr * 128 +
                                       (((n * 16 + row16) * 2) ^ (swz << 4))) =
                        *reinterpret_cast<unsigned short*>(&h);
                }
        asm volatile("s_waitcnt lgkmcnt(0)" ::: "memory");

        // ---- PV + ell ----
        const char* vbuf = (const char*)lds_v[cur];
        __builtin_amdgcn_s_setprio(1);
        #pragma unroll
        for (int kc = 0; kc < 2; ++kc) {
            short8 pf[2];
            #pragma unroll
            for (int m = 0; m < 2; ++m) {
                pf[m] = *(const short8*)((const char*)lds_p[wv] + (m * 16 + row16) * 128 +
                                         ((kc * 64 + g * 16) ^ (swzr << 4)));
                ellacc[m] = __builtin_amdgcn_mfma_f32_16x16x32_bf16(pf[m], ones, ellacc[m], 0, 0, 0);
            }
            #pragma unroll
            for (int n2 = 0; n2 < 8; ++n2) {
                int vrow = n2 * 16 + row16;
                short8 vf = *(const short8*)(vbuf + vrow * 128 +
                                             ((kc * 64 + g * 16) ^ ((vrow & 7) << 4)));
                #pragma unroll
                for (int m = 0; m < 2; ++m)
                    oacc[m][n2] = __builtin_amdgcn_mfma_f32_16x16x32_bf16(pf[m], vf, oacc[m][n2], 0, 0, 0);
            }
        }
        __builtin_amdgcn_s_setprio(0);

        asm volatile("s_waitcnt vmcnt(0)" ::: "memory");  // next tile staged
        __syncthreads();
        cur ^= 1;
    }

    // ---- epilogue: O / ell ----
    float* ob = og + ((size_t)b * NQ + q0) * DH;
    #pragma unroll
    for (int m = 0; m < 2; ++m) {
        float rl[4];
        #pragma unroll
        for (int r = 0; r < 4; ++r) rl[r] = 1.0f / ellacc[m][r];
        #pragma unroll
        for (int n2 = 0; n2 < 8; ++n2)
            #pragma unroll
            for (int r = 0; r < 4; ++r)
                ob[(size_t)(m * 16 + g * 4 + r) * DH + n2 * 16 + row16] = oacc[m][n2][r] * rl[r];
    }
}

extern "C" void kernel_launch(void* const* d_in, const int* in_sizes, int n_in,
                              void* d_out, int out_size, void* d_ws, size_t ws_size,
                              hipStream_t stream) {
    const float* q  = (const float*)d_in[0];
    const float* k  = (const float*)d_in[1];
    const float* v  = (const float*)d_in[2];
    const int*   vl = (const int*)d_in[3];
    float* o = (float*)d_out;

    unsigned short* kws = (unsigned short*)d_ws;
    unsigned short* vws = (unsigned short*)((char*)d_ws + (size_t)NB * NTILE * TILE_BYTES);
    preconv<<<dim3(NB * NTILE), dim3(256), 0, stream>>>(k, v, vl, kws, vws);
    attn_fwd4<<<dim3(NB * 16), dim3(256), 0, stream>>>(q, kws, vws, vl, o);
}

// Round 5
// 76.115 us; speedup vs baseline: 1.0248x; 1.0248x over previous
//
#include <hip/hip_runtime.h>
#include <hip/hip_bf16.h>

#define NB    16
#define NQ    2048
#define NKV   2048
#define DH    128
#define KVT   64
#define NTILE 32          // NKV / KVT
#define TILE_BYTES 16384  // 64*128*2
#define TILE_ELT   8192

typedef __attribute__((ext_vector_type(8))) short short8;
typedef __attribute__((ext_vector_type(4))) float f32x4;

__device__ __forceinline__ unsigned short f2bf(float f) {
    union { float f; unsigned int u; } x; x.f = f;
    unsigned int r = (x.u + 0x7fffu + ((x.u >> 16) & 1u)) >> 16;
    return (unsigned short)r;
}

__device__ __forceinline__ void load_lds16(const void* g, void* l) {
    __builtin_amdgcn_global_load_lds(
        (const __attribute__((address_space(1))) unsigned int*)g,
        (__attribute__((address_space(3))) unsigned int*)l, 16, 0, 0);
}

// ---------------- pre-convert K -> bf16 tiles, V -> V^T bf16 tiles -----------
__global__ __launch_bounds__(256)
void preconv(const float* __restrict__ kg, const float* __restrict__ vg,
             const int* __restrict__ vlg,
             unsigned short* __restrict__ kws, unsigned short* __restrict__ vws) {
    __shared__ __align__(16) unsigned short lv[TILE_ELT];   // 16 KB temp
    const int tid = threadIdx.x;
    const int rb = (blockIdx.x & 7) * 64 + (blockIdx.x >> 3);   // XCD chunking
    const int b = rb >> 5, t = rb & 31;
    const int vl = vlg[b];
    const int ntiles = (vl == 0) ? NTILE : ((vl + KVT - 1) >> 6);
    if (t >= ntiles) return;

    const float* kb = kg + ((size_t)b * NKV + t * KVT) * DH;
    const float* vb = vg + ((size_t)b * NKV + t * KVT) * DH;
    char* kimg = (char*)(kws + (size_t)(b * NTILE + t) * TILE_ELT);
    char* vimg = (char*)(vws + (size_t)(b * NTILE + t) * TILE_ELT);

    #pragma unroll
    for (int p = 0; p < 4; ++p) {
        int idx = p * 256 + tid;
        int row = idx >> 4, ch = idx & 15;
        f32x4 a = *(const f32x4*)(kb + row * DH + ch * 8);
        f32x4 c = *(const f32x4*)(kb + row * DH + ch * 8 + 4);
        union { short8 v; unsigned short u[8]; } w;
        #pragma unroll
        for (int j = 0; j < 4; ++j) { w.u[j] = f2bf(a[j]); w.u[4 + j] = f2bf(c[j]); }
        *(short8*)(kimg + row * 256 + ((ch * 16) ^ ((row & 7) << 4))) = w.v;
        f32x4 va = *(const f32x4*)(vb + row * DH + ch * 8);
        f32x4 vc = *(const f32x4*)(vb + row * DH + ch * 8 + 4);
        union { short8 v; unsigned short u[8]; } w2;
        #pragma unroll
        for (int j = 0; j < 4; ++j) { w2.u[j] = f2bf(va[j]); w2.u[4 + j] = f2bf(vc[j]); }
        *(short8*)((char*)lv + row * 256 + ((ch * 16) ^ (((row >> 3) & 7) << 4))) = w2.v;
    }
    __syncthreads();
    #pragma unroll
    for (int p = 0; p < 4; ++p) {
        int task = p * 256 + tid;
        int c = task & 7, d = task >> 3;
        union { short8 v; unsigned short u[8]; } w;
        #pragma unroll
        for (int j = 0; j < 8; ++j) {
            int kv = c * 8 + j;
            w.u[j] = *(const unsigned short*)((const char*)lv + kv * 256 + ((d * 2) ^ (((kv >> 3) & 7) << 4)));
        }
        *(short8*)(vimg + d * 128 + ((c * 16) ^ ((d & 7) << 4))) = w.v;
    }
}

// ------- split-KV attention: 4 waves x 16 q-rows, interleaved tile splits ----
__global__ __launch_bounds__(256, 4)
void attn_split(const float* __restrict__ qg,
                const unsigned short* __restrict__ kws,
                const unsigned short* __restrict__ vws,
                const int* __restrict__ vlg,
                float* __restrict__ og,       // used when S==1
                float* __restrict__ opart,    // [S][NB][NQ][DH] unnormalized
                float* __restrict__ ellg,     // [S][NB][NQ]
                int S) {
    __shared__ __align__(16) unsigned short lds_k[TILE_ELT];      // 16 KB
    __shared__ __align__(16) unsigned short lds_v[TILE_ELT];      // 16 KB
    __shared__ __align__(16) unsigned short lds_p[4][16 * KVT];   // 8 KB

    const int tid = threadIdx.x;
    const int lane = tid & 63;
    const int wv = tid >> 6;
    const int row16 = lane & 15;
    const int g = lane >> 4;

    const int bid = blockIdx.x;
    const int b    = bid & 15;           // consecutive bids -> different batches
    const int rest = bid >> 4;
    const int qt   = rest & 31;          // 0..31 (64 q-rows each)
    const int s    = rest >> 5;          // split id
    const int q0   = qt * 64 + wv * 16;
    const int vl = vlg[b];

    const int nt = (vl == 0) ? NTILE : ((vl + KVT - 1) >> 6);

    if (s >= nt) {
        // inactive split: mark ell = 0 for our 64 rows (ws is poisoned!)
        if (tid < 64)
            ellg[(size_t)s * NB * NQ + (size_t)b * NQ + qt * 64 + tid] = 0.f;
        return;
    }

    // Q fragments; scale folded: (1/sqrt(128)) * log2(e)
    const float QS = 1.4426950408889634f * 0.08838834764831845f;
    short8 qf[4];
    {
        const float* qp = qg + ((size_t)b * NQ + q0 + row16) * DH + g * 8;
        #pragma unroll
        for (int c = 0; c < 4; ++c) {
            f32x4 a  = *(const f32x4*)(qp + c * 32);
            f32x4 bb = *(const f32x4*)(qp + c * 32 + 4);
            union { short8 v; unsigned short u[8]; } t;
            #pragma unroll
            for (int j = 0; j < 4; ++j) { t.u[j] = f2bf(a[j] * QS); t.u[4 + j] = f2bf(bb[j] * QS); }
            qf[c] = t.v;
        }
    }

    // unnormalized softmax: P = exp2(s); masked -> 0 exactly. vl==0 -> uniform.
    const float MASKV = (vl == 0) ? 0.0f : -1442695.0f;

    f32x4 oacc[8];
    f32x4 ellacc = (f32x4){0.f, 0.f, 0.f, 0.f};
    #pragma unroll
    for (int n = 0; n < 8; ++n) oacc[n] = (f32x4){0.f, 0.f, 0.f, 0.f};
    short8 ones;
    {
        union { short8 v; unsigned short u[8]; } t;
        #pragma unroll
        for (int j = 0; j < 8; ++j) t.u[j] = 0x3F80;  // bf16 1.0
        ones = t.v;
    }

    const char* kbase = (const char*)kws + (size_t)b * NTILE * TILE_BYTES;
    const char* vbase = (const char*)vws + (size_t)b * NTILE * TILE_BYTES;
    const int swzr = ((row16 >> 2) ^ ((row16 & 3) << 1)) & 7;

    for (int tt = s; tt < nt; tt += S) {
        // ---- stage K and V (single-buffered; TLP from 4 blocks/CU hides it) ----
        const char* ks = kbase + (size_t)tt * TILE_BYTES;
        const char* vs = vbase + (size_t)tt * TILE_BYTES;
        #pragma unroll
        for (int i = 0; i < 4; ++i) {
            int off = i * 4096 + wv * 1024;
            load_lds16(ks + off + lane * 16, (char*)lds_k + off);
            load_lds16(vs + off + lane * 16, (char*)lds_v + off);
        }
        asm volatile("s_waitcnt vmcnt(0)" ::: "memory");
        __syncthreads();

        // ---- QK^T ----
        f32x4 sc[4];
        #pragma unroll
        for (int n = 0; n < 4; ++n) sc[n] = (f32x4){0.f, 0.f, 0.f, 0.f};
        __builtin_amdgcn_s_setprio(1);
        #pragma unroll
        for (int c = 0; c < 4; ++c) {
            short8 kf[4];
            #pragma unroll
            for (int n = 0; n < 4; ++n) {
                int krow = n * 16 + row16;
                kf[n] = *(const short8*)((const char*)lds_k + krow * 256 +
                                         ((c * 64 + g * 16) ^ ((krow & 7) << 4)));
            }
            #pragma unroll
            for (int n = 0; n < 4; ++n)
                sc[n] = __builtin_amdgcn_mfma_f32_16x16x32_bf16(qf[c], kf[n], sc[n], 0, 0, 0);
        }
        __builtin_amdgcn_s_setprio(0);

        // ---- mask (global last tile only; vl==0 masks all to 0) ----
        if (vl == 0 || tt == nt - 1) {
            int kvb = tt * KVT;
            #pragma unroll
            for (int n = 0; n < 4; ++n) {
                if (kvb + n * 16 + row16 >= vl) {
                    #pragma unroll
                    for (int r = 0; r < 4; ++r) sc[n][r] = MASKV;
                }
            }
        }

        // ---- P = exp2(s) -> per-wave LDS (swizzled, conflict-light) ----
        #pragma unroll
        for (int n = 0; n < 4; ++n)
            #pragma unroll
            for (int r = 0; r < 4; ++r) {
                float p = __builtin_amdgcn_exp2f(sc[n][r]);
                int qr = g * 4 + r;
                int swz = (g ^ (r << 1)) & 7;
                __hip_bfloat16 h = __float2bfloat16(p);
                *(unsigned short*)((char*)lds_p[wv] + qr * 128 +
                                   (((n * 16 + row16) * 2) ^ (swz << 4))) =
                    *reinterpret_cast<unsigned short*>(&h);
            }
        asm volatile("s_waitcnt lgkmcnt(0)" ::: "memory");

        // ---- PV + ell (ones-column MFMA) ----
        __builtin_amdgcn_s_setprio(1);
        #pragma unroll
        for (int kc = 0; kc < 2; ++kc) {
            short8 pf = *(const short8*)((const char*)lds_p[wv] + row16 * 128 +
                                         ((kc * 64 + g * 16) ^ (swzr << 4)));
            ellacc = __builtin_amdgcn_mfma_f32_16x16x32_bf16(pf, ones, ellacc, 0, 0, 0);
            #pragma unroll
            for (int n2 = 0; n2 < 8; ++n2) {
                int vrow = n2 * 16 + row16;
                short8 vf = *(const short8*)((const char*)lds_v + vrow * 128 +
                                             ((kc * 64 + g * 16) ^ ((vrow & 7) << 4)));
                oacc[n2] = __builtin_amdgcn_mfma_f32_16x16x32_bf16(pf, vf, oacc[n2], 0, 0, 0);
            }
        }
        __builtin_amdgcn_s_setprio(0);

        __syncthreads();   // all waves done reading before next stage overwrites
    }

    if (S == 1) {
        // direct normalized output
        float* ob = og + ((size_t)b * NQ + q0) * DH;
        float rl[4];
        #pragma unroll
        for (int r = 0; r < 4; ++r) rl[r] = 1.0f / ellacc[r];
        #pragma unroll
        for (int n2 = 0; n2 < 8; ++n2)
            #pragma unroll
            for (int r = 0; r < 4; ++r)
                ob[(size_t)(g * 4 + r) * DH + n2 * 16 + row16] = oacc[n2][r] * rl[r];
    } else {
        // unnormalized partials
        float* op = opart + ((size_t)s * NB * NQ + (size_t)b * NQ + q0) * DH;
        #pragma unroll
        for (int n2 = 0; n2 < 8; ++n2)
            #pragma unroll
            for (int r = 0; r < 4; ++r)
                op[(size_t)(g * 4 + r) * DH + n2 * 16 + row16] = oacc[n2][r];
        if (row16 == 0) {
            float* el = ellg + (size_t)s * NB * NQ + (size_t)b * NQ + q0;
            #pragma unroll
            for (int r = 0; r < 4; ++r) el[g * 4 + r] = ellacc[r];
        }
    }
}

// ---------------- combine: out = sum_s O_s / sum_s ell_s --------------------
__global__ __launch_bounds__(256)
void combine(const float* __restrict__ opart, const float* __restrict__ ellg,
             float* __restrict__ og, int S) {
    int idx = blockIdx.x * 256 + threadIdx.x;   // NB*NQ*32 threads
    int row = idx >> 5;                          // b*NQ + q
    int c   = idx & 31;                          // float4 chunk of DH
    f32x4 acc = (f32x4){0.f, 0.f, 0.f, 0.f};
    float l = 0.f;
    for (int s = 0; s < S; ++s) {
        float le = ellg[(size_t)s * NB * NQ + row];
        if (le != 0.f) {
            acc += ((const f32x4*)opart)[((size_t)s * NB * NQ + row) * 32 + c];
            l += le;
        }
    }
    float rl = 1.0f / l;
    ((f32x4*)og)[(size_t)row * 32 + c] = acc * rl;
}

extern "C" void kernel_launch(void* const* d_in, const int* in_sizes, int n_in,
                              void* d_out, int out_size, void* d_ws, size_t ws_size,
                              hipStream_t stream) {
    const float* q  = (const float*)d_in[0];
    const float* k  = (const float*)d_in[1];
    const float* v  = (const float*)d_in[2];
    const int*   vl = (const int*)d_in[3];
    float* o = (float*)d_out;

    const size_t IMG = (size_t)NB * NTILE * TILE_BYTES;        // 8 MB
    const size_t ELL_OFF = 2 * IMG;                            // 16 MB
    const size_t ELL_MAX = (size_t)4 * NB * NQ * 4;            // 512 KB
    const size_t OP_OFF  = ELL_OFF + ELL_MAX;
    const size_t OP_ONE  = (size_t)NB * NQ * DH * 4;           // 16 MB per split

    int S = 1;
    if (ws_size >= OP_OFF + 4 * OP_ONE) S = 4;
    else if (ws_size >= OP_OFF + 2 * OP_ONE) S = 2;

    unsigned short* kws = (unsigned short*)d_ws;
    unsigned short* vws = (unsigned short*)((char*)d_ws + IMG);
    float* ellg  = (float*)((char*)d_ws + ELL_OFF);
    float* opart = (float*)((char*)d_ws + OP_OFF);

    preconv<<<dim3(NB * NTILE), dim3(256), 0, stream>>>(k, v, vl, kws, vws);
    attn_split<<<dim3(NB * 32 * S), dim3(256), 0, stream>>>(q, kws, vws, vl, o, opart, ellg, S);
    if (S > 1)
        combine<<<dim3(NB * NQ * 32 / 256), dim3(256), 0, stream>>>(opart, ellg, o, S);
}

// Round 6
// 74.661 us; speedup vs baseline: 1.0447x; 1.0195x over previous
//
#include <hip/hip_runtime.h>
#include <hip/hip_bf16.h>

#define NB    16
#define NQ    2048
#define NKV   2048
#define DH    128
#define KVT   64
#define NTILE 32          // NKV / KVT
#define TILE_BYTES 16384  // 64*128*2
#define TILE_ELT   8192

typedef __attribute__((ext_vector_type(8))) short short8;
typedef __attribute__((ext_vector_type(4))) float f32x4;

__device__ __forceinline__ unsigned short f2bf(float f) {
    union { float f; unsigned int u; } x; x.f = f;
    unsigned int r = (x.u + 0x7fffu + ((x.u >> 16) & 1u)) >> 16;
    return (unsigned short)r;
}

__device__ __forceinline__ void load_lds16(const void* g, void* l) {
    __builtin_amdgcn_global_load_lds(
        (const __attribute__((address_space(1))) unsigned int*)g,
        (__attribute__((address_space(3))) unsigned int*)l, 16, 0, 0);
}

// ---------------- pre-convert K -> bf16 tiles, V -> V^T bf16 tiles -----------
__global__ __launch_bounds__(256)
void preconv(const float* __restrict__ kg, const float* __restrict__ vg,
             const int* __restrict__ vlg,
             unsigned short* __restrict__ kws, unsigned short* __restrict__ vws) {
    __shared__ __align__(16) unsigned short lv[TILE_ELT];   // 16 KB temp
    const int tid = threadIdx.x;
    const int rb = (blockIdx.x & 7) * 64 + (blockIdx.x >> 3);   // XCD chunking
    const int b = rb >> 5, t = rb & 31;
    const int vl = vlg[b];
    const int ntiles = (vl == 0) ? NTILE : ((vl + KVT - 1) >> 6);
    if (t >= ntiles) return;

    const float* kb = kg + ((size_t)b * NKV + t * KVT) * DH;
    const float* vb = vg + ((size_t)b * NKV + t * KVT) * DH;
    char* kimg = (char*)(kws + (size_t)(b * NTILE + t) * TILE_ELT);
    char* vimg = (char*)(vws + (size_t)(b * NTILE + t) * TILE_ELT);

    #pragma unroll
    for (int p = 0; p < 4; ++p) {
        int idx = p * 256 + tid;
        int row = idx >> 4, ch = idx & 15;
        f32x4 a = *(const f32x4*)(kb + row * DH + ch * 8);
        f32x4 c = *(const f32x4*)(kb + row * DH + ch * 8 + 4);
        union { short8 v; unsigned short u[8]; } w;
        #pragma unroll
        for (int j = 0; j < 4; ++j) { w.u[j] = f2bf(a[j]); w.u[4 + j] = f2bf(c[j]); }
        *(short8*)(kimg + row * 256 + ((ch * 16) ^ ((row & 7) << 4))) = w.v;
        f32x4 va = *(const f32x4*)(vb + row * DH + ch * 8);
        f32x4 vc = *(const f32x4*)(vb + row * DH + ch * 8 + 4);
        union { short8 v; unsigned short u[8]; } w2;
        #pragma unroll
        for (int j = 0; j < 4; ++j) { w2.u[j] = f2bf(va[j]); w2.u[4 + j] = f2bf(vc[j]); }
        *(short8*)((char*)lv + row * 256 + ((ch * 16) ^ (((row >> 3) & 7) << 4))) = w2.v;
    }
    __syncthreads();
    #pragma unroll
    for (int p = 0; p < 4; ++p) {
        int task = p * 256 + tid;
        int c = task & 7, d = task >> 3;
        union { short8 v; unsigned short u[8]; } w;
        #pragma unroll
        for (int j = 0; j < 8; ++j) {
            int kv = c * 8 + j;
            w.u[j] = *(const unsigned short*)((const char*)lv + kv * 256 + ((d * 2) ^ (((kv >> 3) & 7) << 4)));
        }
        *(short8*)(vimg + d * 128 + ((c * 16) ^ ((d & 7) << 4))) = w.v;
    }
}

// ------- split-KV attention: 4 waves x 16 q-rows, permuted work mapping -----
__global__ __launch_bounds__(256, 4)
void attn_split(const float* __restrict__ qg,
                const unsigned short* __restrict__ kws,
                const unsigned short* __restrict__ vws,
                const int* __restrict__ vlg,
                float* __restrict__ og,       // used when S==1
                float* __restrict__ opart,    // [S][NB][NQ][DH] unnormalized
                float* __restrict__ ellg,     // [S][NB][NQ]
                int S, int gmask) {
    __shared__ __align__(16) unsigned short lds_k[TILE_ELT];      // 16 KB
    __shared__ __align__(16) unsigned short lds_v[TILE_ELT];      // 16 KB
    __shared__ __align__(16) unsigned short lds_p[4][16 * KVT];   // 8 KB

    const int tid = threadIdx.x;
    const int lane = tid & 63;
    const int wv = tid >> 6;
    const int row16 = lane & 15;
    const int g = lane >> 4;

    // DECORRELATE work-item from CU: dispatch is ~round-robin over 256 CUs, so
    // decoding batch from raw bid makes co-resident blocks share a batch ->
    // massive work skew (vl in 0..2047). Odd-multiplier perm is bijective on
    // the pow2 grid and mixes (b,qt,s) across each CU's resident blocks.
    const int wid = (blockIdx.x * 1031) & gmask;
    const int b    = wid & 15;
    const int rest = wid >> 4;
    const int qt   = rest & 31;          // 0..31 (64 q-rows each)
    const int s    = rest >> 5;          // split id
    const int q0   = qt * 64 + wv * 16;
    const int vl = vlg[b];

    const int nt = (vl == 0) ? NTILE : ((vl + KVT - 1) >> 6);

    if (s >= nt) {
        // inactive split: mark ell = 0 for our 64 rows (ws is poisoned!)
        if (tid < 64)
            ellg[(size_t)s * NB * NQ + (size_t)b * NQ + qt * 64 + tid] = 0.f;
        return;
    }

    // Q fragments; scale folded: (1/sqrt(128)) * log2(e)
    const float QS = 1.4426950408889634f * 0.08838834764831845f;
    short8 qf[4];
    {
        const float* qp = qg + ((size_t)b * NQ + q0 + row16) * DH + g * 8;
        #pragma unroll
        for (int c = 0; c < 4; ++c) {
            f32x4 a  = *(const f32x4*)(qp + c * 32);
            f32x4 bb = *(const f32x4*)(qp + c * 32 + 4);
            union { short8 v; unsigned short u[8]; } t;
            #pragma unroll
            for (int j = 0; j < 4; ++j) { t.u[j] = f2bf(a[j] * QS); t.u[4 + j] = f2bf(bb[j] * QS); }
            qf[c] = t.v;
        }
    }

    // unnormalized softmax: P = exp2(s); masked -> 0 exactly. vl==0 -> uniform.
    const float MASKV = (vl == 0) ? 0.0f : -1442695.0f;

    f32x4 oacc[8];
    f32x4 ellacc = (f32x4){0.f, 0.f, 0.f, 0.f};
    #pragma unroll
    for (int n = 0; n < 8; ++n) oacc[n] = (f32x4){0.f, 0.f, 0.f, 0.f};
    short8 ones;
    {
        union { short8 v; unsigned short u[8]; } t;
        #pragma unroll
        for (int j = 0; j < 8; ++j) t.u[j] = 0x3F80;  // bf16 1.0
        ones = t.v;
    }

    const char* kbase = (const char*)kws + (size_t)b * NTILE * TILE_BYTES;
    const char* vbase = (const char*)vws + (size_t)b * NTILE * TILE_BYTES;
    const int swzr = ((row16 >> 2) ^ ((row16 & 3) << 1)) & 7;

    for (int tt = s; tt < nt; tt += S) {
        // ---- stage K and V (single-buffered; TLP from 4 blocks/CU hides it) ----
        const char* ks = kbase + (size_t)tt * TILE_BYTES;
        const char* vs = vbase + (size_t)tt * TILE_BYTES;
        #pragma unroll
        for (int i = 0; i < 4; ++i) {
            int off = i * 4096 + wv * 1024;
            load_lds16(ks + off + lane * 16, (char*)lds_k + off);
            load_lds16(vs + off + lane * 16, (char*)lds_v + off);
        }
        asm volatile("s_waitcnt vmcnt(0)" ::: "memory");
        __syncthreads();

        // ---- QK^T ----
        f32x4 sc[4];
        #pragma unroll
        for (int n = 0; n < 4; ++n) sc[n] = (f32x4){0.f, 0.f, 0.f, 0.f};
        __builtin_amdgcn_s_setprio(1);
        #pragma unroll
        for (int c = 0; c < 4; ++c) {
            short8 kf[4];
            #pragma unroll
            for (int n = 0; n < 4; ++n) {
                int krow = n * 16 + row16;
                kf[n] = *(const short8*)((const char*)lds_k + krow * 256 +
                                         ((c * 64 + g * 16) ^ ((krow & 7) << 4)));
            }
            #pragma unroll
            for (int n = 0; n < 4; ++n)
                sc[n] = __builtin_amdgcn_mfma_f32_16x16x32_bf16(qf[c], kf[n], sc[n], 0, 0, 0);
        }
        __builtin_amdgcn_s_setprio(0);

        // ---- mask (global last tile only; vl==0 masks all to 0) ----
        if (vl == 0 || tt == nt - 1) {
            int kvb = tt * KVT;
            #pragma unroll
            for (int n = 0; n < 4; ++n) {
                if (kvb + n * 16 + row16 >= vl) {
                    #pragma unroll
                    for (int r = 0; r < 4; ++r) sc[n][r] = MASKV;
                }
            }
        }

        // ---- P = exp2(s) -> per-wave LDS (swizzled, conflict-light) ----
        #pragma unroll
        for (int n = 0; n < 4; ++n)
            #pragma unroll
            for (int r = 0; r < 4; ++r) {
                float p = __builtin_amdgcn_exp2f(sc[n][r]);
                int qr = g * 4 + r;
                int swz = (g ^ (r << 1)) & 7;
                __hip_bfloat16 h = __float2bfloat16(p);
                *(unsigned short*)((char*)lds_p[wv] + qr * 128 +
                                   (((n * 16 + row16) * 2) ^ (swz << 4))) =
                    *reinterpret_cast<unsigned short*>(&h);
            }
        asm volatile("s_waitcnt lgkmcnt(0)" ::: "memory");

        // ---- PV + ell (ones-column MFMA) ----
        __builtin_amdgcn_s_setprio(1);
        #pragma unroll
        for (int kc = 0; kc < 2; ++kc) {
            short8 pf = *(const short8*)((const char*)lds_p[wv] + row16 * 128 +
                                         ((kc * 64 + g * 16) ^ (swzr << 4)));
            ellacc = __builtin_amdgcn_mfma_f32_16x16x32_bf16(pf, ones, ellacc, 0, 0, 0);
            #pragma unroll
            for (int n2 = 0; n2 < 8; ++n2) {
                int vrow = n2 * 16 + row16;
                short8 vf = *(const short8*)((const char*)lds_v + vrow * 128 +
                                             ((kc * 64 + g * 16) ^ ((vrow & 7) << 4)));
                oacc[n2] = __builtin_amdgcn_mfma_f32_16x16x32_bf16(pf, vf, oacc[n2], 0, 0, 0);
            }
        }
        __builtin_amdgcn_s_setprio(0);

        __syncthreads();   // all waves done reading before next stage overwrites
    }

    if (S == 1) {
        float* ob = og + ((size_t)b * NQ + q0) * DH;
        float rl[4];
        #pragma unroll
        for (int r = 0; r < 4; ++r) rl[r] = 1.0f / ellacc[r];
        #pragma unroll
        for (int n2 = 0; n2 < 8; ++n2)
            #pragma unroll
            for (int r = 0; r < 4; ++r)
                ob[(size_t)(g * 4 + r) * DH + n2 * 16 + row16] = oacc[n2][r] * rl[r];
    } else {
        float* op = opart + ((size_t)s * NB * NQ + (size_t)b * NQ + q0) * DH;
        #pragma unroll
        for (int n2 = 0; n2 < 8; ++n2)
            #pragma unroll
            for (int r = 0; r < 4; ++r)
                op[(size_t)(g * 4 + r) * DH + n2 * 16 + row16] = oacc[n2][r];
        if (row16 == 0) {
            float* el = ellg + (size_t)s * NB * NQ + (size_t)b * NQ + q0;
            #pragma unroll
            for (int r = 0; r < 4; ++r) el[g * 4 + r] = ellacc[r];
        }
    }
}

// ---------------- combine: out = sum_s O_s / sum_s ell_s --------------------
__global__ __launch_bounds__(256)
void combine(const float* __restrict__ opart, const float* __restrict__ ellg,
             float* __restrict__ og, int S) {
    int idx = blockIdx.x * 256 + threadIdx.x;   // NB*NQ*32 threads
    int row = idx >> 5;                          // b*NQ + q
    int c   = idx & 31;                          // float4 chunk of DH
    f32x4 acc = (f32x4){0.f, 0.f, 0.f, 0.f};
    float l = 0.f;
    for (int s = 0; s < S; ++s) {
        float le = ellg[(size_t)s * NB * NQ + row];
        if (le != 0.f) {
            acc += ((const f32x4*)opart)[((size_t)s * NB * NQ + row) * 32 + c];
            l += le;
        }
    }
    float rl = 1.0f / l;
    ((f32x4*)og)[(size_t)row * 32 + c] = acc * rl;
}

extern "C" void kernel_launch(void* const* d_in, const int* in_sizes, int n_in,
                              void* d_out, int out_size, void* d_ws, size_t ws_size,
                              hipStream_t stream) {
    const float* q  = (const float*)d_in[0];
    const float* k  = (const float*)d_in[1];
    const float* v  = (const float*)d_in[2];
    const int*   vl = (const int*)d_in[3];
    float* o = (float*)d_out;

    const size_t IMG = (size_t)NB * NTILE * TILE_BYTES;        // 8 MB
    const size_t ELL_OFF = 2 * IMG;                            // 16 MB
    const size_t ELL_MAX = (size_t)4 * NB * NQ * 4;            // 512 KB
    const size_t OP_OFF  = ELL_OFF + ELL_MAX;
    const size_t OP_ONE  = (size_t)NB * NQ * DH * 4;           // 16 MB per split

    int S = 1;
    if (ws_size >= OP_OFF + 4 * OP_ONE) S = 4;
    else if (ws_size >= OP_OFF + 2 * OP_ONE) S = 2;

    unsigned short* kws = (unsigned short*)d_ws;
    unsigned short* vws = (unsigned short*)((char*)d_ws + IMG);
    float* ellg  = (float*)((char*)d_ws + ELL_OFF);
    float* opart = (float*)((char*)d_ws + OP_OFF);

    int grid = NB * 32 * S;                 // power of two for S in {1,2,4}
    preconv<<<dim3(NB * NTILE), dim3(256), 0, stream>>>(k, v, vl, kws, vws);
    attn_split<<<dim3(grid), dim3(256), 0, stream>>>(q, kws, vws, vl, o, opart, ellg, S, grid - 1);
    if (S > 1)
        combine<<<dim3(NB * NQ * 32 / 256), dim3(256), 0, stream>>>(opart, ellg, o, S);
}